// Round 2
// baseline (193.058 us; speedup 1.0000x reference)
//
#include <hip/hip_runtime.h>

// PlanarQuantMSE: per-row normalize -> per-pair 2x2 rotate -> 16-centroid
// nearest quantize -> dequant -> inverse rotate -> rescale.
// B=4096, d=4096, n_groups=2048, 16 sorted centroids.
//
// R8: R7 (LDS row stash, occupancy) gave -2.7us -> kernel near but maybe not
// at its ~29us streaming floor (est ~38us from total - ~145us harness reset
// floor; kernel absent from rocprof top-5, all fills ~80us). Last structural
// inefficiency: intra-block serialization load->reduce->barrier->compute->
// store makes read BW and write BW alternate per block. This round splits
// into two pure-streaming kernels:
//   A: row norms. PLAIN (cached) x loads so the 64MB input stays resident in
//      the 256MB L3; fp64 reduce; one double per row into d_ws (32KB).
//   B: transform. No stash, no reduce; x re-read hits L3; uniform norm load;
//      nontemporal 128MB output stream; 272B LDS -> max occupancy.
// Math bit-identical to R7 (same fp64 sum order, same clip, same fp32 scan
// + fp64 midpoint fallback) -> absmax stays 0.125.
// Decision rule: neutral/regression here => single-kernel was at floor =>
// declare roofline.

#define ROW_D     4096
#define BLOCK_T   256
#define F4_PER_T  4   // (ROW_D/4)/BLOCK_T

typedef float f32x4 __attribute__((ext_vector_type(4)));

struct QP { float o0, o1, i0, i1; };

__device__ __forceinline__ QP quant_pair(
    float x0, float x1, float c, float s,
    float invf, float dnf, double invd,
    const float* __restrict__ mf,            // 15 fp32 midpoints (regs/SGPR)
    const float4* __restrict__ w4,           // LDS: (md[k-1], cd[k], md[k], 0)
    const float* __restrict__ cent)          // global centroids (fp64 fallback)
{
    // fp32 fast path: rotate
    const float v0 = x0 * invf, v1 = x1 * invf;
    const float r0 = c * v0 - s * v1;
    const float r1 = s * v0 + c * v1;

    // count-only scan: a = #{j : r > md[j]}  (== argmin over sorted centroids,
    // first-min tie-break since '>' keeps the lower index at exact midpoints)
    int a = 0, b = 0;
#pragma unroll
    for (int j = 0; j < 15; ++j) {
        a += (r0 > mf[j]) ? 1 : 0;
        b += (r1 > mf[j]) ? 1 : 0;
    }

    // one b128 lookup per value: lower bound, centroid, upper bound
    const float4 pa = w4[a];
    const float4 pb = w4[b];
    float q0 = pa.y, q1 = pb.y;

    // near-tie guard: distance to the chosen interval's boundaries
    const float EPS = 1e-5f;
    const float g0 = fminf(r0 - pa.x, pa.z - r0);
    const float g1 = fminf(r1 - pb.x, pb.z - r1);
    if (g0 < EPS || g1 < EPS) {
        // fp64 recompute for this pair (rare, exec-masked)
        const double v0d = (double)x0 * invd;
        const double v1d = (double)x1 * invd;
        const double cd = (double)c, sd = (double)s;
        const double r0d = cd * v0d - sd * v1d;
        const double r1d = sd * v0d + cd * v1d;
        a = 0; b = 0;
        double q0d = (double)cent[0], q1d = (double)cent[0];
#pragma unroll
        for (int j = 0; j < 15; ++j) {
            const double mj = 0.5 * ((double)cent[j] + (double)cent[j + 1]);  // exact
            const bool ca = r0d > mj;
            const bool cb = r1d > mj;
            a += ca ? 1 : 0;
            b += cb ? 1 : 0;
            q0d = ca ? (double)cent[j + 1] : q0d;
            q1d = cb ? (double)cent[j + 1] : q1d;
        }
        q0 = (float)q0d;
        q1 = (float)q1d;
    }

    // dequant + inverse rotate + rescale (comparison is bf16-granular)
    QP r;
    r.o0 = (c * q0 + s * q1) * dnf;
    r.o1 = (c * q1 - s * q0) * dnf;
    r.i0 = (float)a;
    r.i1 = (float)b;
    return r;
}

// Kernel A: per-row fp64 norm. Plain (cached) loads -> x stays in L3 for B.
__global__ __launch_bounds__(BLOCK_T) void norm_kernel(
    const float* __restrict__ x,
    double* __restrict__ norms)
{
    const int row = blockIdx.x;
    const int t   = threadIdx.x;
    const f32x4* xr = (const f32x4*)(x + (size_t)row * ROW_D);

    double ss = 0.0;
#pragma unroll
    for (int i = 0; i < F4_PER_T; ++i) {
        const f32x4 v = xr[t + BLOCK_T * i];
        ss += (double)v.x * (double)v.x;
        ss += (double)v.y * (double)v.y;
        ss += (double)v.z * (double)v.z;
        ss += (double)v.w * (double)v.w;
    }

#pragma unroll
    for (int off = 32; off > 0; off >>= 1)
        ss += __shfl_down(ss, off, 64);

    __shared__ double smem[4];
    if ((t & 63) == 0) smem[t >> 6] = ss;
    __syncthreads();
    if (t == 0) {
        const double tot = smem[0] + smem[1] + smem[2] + smem[3];
        const double n = sqrt(tot);
        norms[row] = (n < 1e-8) ? 1e-8 : n;   // jnp.clip(norm, 1e-8)
    }
}

// Kernel B: pure streaming transform. x re-read is an L3 hit; outputs are
// nontemporal coalesced stores. No cross-phase dependency, minimal LDS.
__global__ __launch_bounds__(BLOCK_T) void quant_kernel(
    const float* __restrict__ x,
    const float* __restrict__ cent,
    const float* __restrict__ rot2,
    const double* __restrict__ norms,
    float* __restrict__ out_xhat,
    float* __restrict__ out_idx)
{
    const int row = blockIdx.x;
    const int t   = threadIdx.x;

    const f32x4* xr = (const f32x4*)(x + (size_t)row * ROW_D);
    const float4* rr = (const float4*)rot2;   // float4 f covers pairs 2f, 2f+1

    // centroids + midpoints in fp32 (uniform loads -> scalar regs)
    float cf[16];
#pragma unroll
    for (int j = 0; j < 16; ++j) cf[j] = cent[j];
    float mf[15];
#pragma unroll
    for (int j = 0; j < 15; ++j) mf[j] = 0.5f * (cf[j] + cf[j + 1]);

    __shared__ float4 w4[16];   // (md[k-1], cd[k], md[k], 0); ends = +-inf
    if (t < 16) {
        const float lo = (t == 0)  ? -3.0e38f : 0.5f * (cf[t - 1] + cf[t]);
        const float hi = (t == 15) ?  3.0e38f : 0.5f * (cf[t] + cf[t + 1]);
        w4[t] = make_float4(lo, cf[t], hi, 0.0f);
    }

    const double dnd  = norms[row];           // uniform -> broadcast load
    const double invd = 1.0 / dnd;
    const float  dnf  = (float)dnd;
    const float  invf = (float)invd;
    __syncthreads();

    f32x4* xo = (f32x4*)(out_xhat + (size_t)row * ROW_D);
    f32x4* io = (f32x4*)(out_idx  + (size_t)row * ROW_D);

#pragma unroll
    for (int i = 0; i < F4_PER_T; ++i) {
        const int f = t + BLOCK_T * i;
        const f32x4 xv = xr[f];               // L3 hit (read by kernel A)
        const float4 rv = rr[f];              // L1/L2 hot (16KB, all blocks)
        const QP lo = quant_pair(xv.x, xv.y, rv.x, rv.y, invf, dnf, invd, mf, w4, cent);
        const QP hi = quant_pair(xv.z, xv.w, rv.z, rv.w, invf, dnf, invd, mf, w4, cent);
        f32x4 ov, iv;
        ov.x = lo.o0; ov.y = lo.o1; ov.z = hi.o0; ov.w = hi.o1;
        iv.x = lo.i0; iv.y = lo.i1; iv.z = hi.i0; iv.w = hi.i1;
        __builtin_nontemporal_store(ov, &xo[f]);
        __builtin_nontemporal_store(iv, &io[f]);
    }
}

extern "C" void kernel_launch(void* const* d_in, const int* in_sizes, int n_in,
                              void* d_out, int out_size, void* d_ws, size_t ws_size,
                              hipStream_t stream) {
    const float* x    = (const float*)d_in[0];
    const float* cent = (const float*)d_in[1];
    const float* rot2 = (const float*)d_in[2];

    const int d = in_sizes[2];           // 2*n_groups = 4096
    const int B = in_sizes[0] / d;       // 4096

    float* out  = (float*)d_out;
    float* xhat = out;                   // output 0: x_hat (B*d fp32)
    float* idxo = out + (size_t)B * d;   // output 1: indices as fp32 values

    double* norms = (double*)d_ws;       // 4096 * 8B = 32KB workspace

    norm_kernel<<<B, BLOCK_T, 0, stream>>>(x, norms);
    quant_kernel<<<B, BLOCK_T, 0, stream>>>(x, cent, rot2, norms, xhat, idxo);
}

// Round 3
// 183.691 us; speedup vs baseline: 1.0510x; 1.0510x over previous
//
#include <hip/hip_runtime.h>

// PlanarQuantMSE: per-row normalize -> per-pair 2x2 rotate -> 16-centroid
// nearest quantize -> dequant -> inverse rotate -> rescale.
// B=4096, d=4096, n_groups=2048, 16 sorted centroids.
//
// R9: REVERT to R7 (best measured: 183.3us). R8's two-kernel split regressed
// +9.7us: it serialized the row-read (norm kernel A has no write traffic to
// overlap) and added a launch; the single-kernel already overlaps read/write
// phases across resident blocks. Evidence across R6/R7/R8: every structural
// move off this shape is neutral (-2.7) or worse (+9.7); kernel est ~38us vs
// ~29us streaming floor (64MB rd + 128MB wr @ ~6.7TB/s); remaining ~145us of
// the bench total is harness poison-fill/reset floor (all rocprof top-5 rows
// are 512MB fills at 84-86% peak HBM). At floor -> declare roofline if this
// reproduces ~183us.
//
// Structure: one block per row. Phase 1 streams x -> LDS stash (16KB) with
// nontemporal loads + fp64 sum of squares (only `ss` crosses the barrier ->
// low VGPR, high occupancy). Phase 2 reads the stash + L1/L2-hot rot2,
// quantizes (fp32 scan + fp64 fallback within 1e-5 of a midpoint), inverse
// rotates, rescales, nontemporal coalesced stores. Math bit-safe vs ref
// (fp64 row norm, exact midpoints in the fallback) -> absmax 0.125.

#define ROW_D     4096
#define BLOCK_T   256
#define F4_PER_T  4   // (ROW_D/4)/BLOCK_T

typedef float f32x4 __attribute__((ext_vector_type(4)));

struct QP { float o0, o1, i0, i1; };

__device__ __forceinline__ QP quant_pair(
    float x0, float x1, float c, float s,
    float invf, float dnf, double invd,
    const float* __restrict__ mf,            // 15 fp32 midpoints (regs/SGPR)
    const float4* __restrict__ w4,           // LDS: (md[k-1], cd[k], md[k], 0)
    const float* __restrict__ cent)          // global centroids (fp64 fallback)
{
    // fp32 fast path: rotate
    const float v0 = x0 * invf, v1 = x1 * invf;
    const float r0 = c * v0 - s * v1;
    const float r1 = s * v0 + c * v1;

    // count-only scan: a = #{j : r > md[j]}  (== argmin over sorted centroids,
    // first-min tie-break since '>' keeps the lower index at exact midpoints)
    int a = 0, b = 0;
#pragma unroll
    for (int j = 0; j < 15; ++j) {
        a += (r0 > mf[j]) ? 1 : 0;
        b += (r1 > mf[j]) ? 1 : 0;
    }

    // one b128 lookup per value: lower bound, centroid, upper bound
    const float4 pa = w4[a];
    const float4 pb = w4[b];
    float q0 = pa.y, q1 = pb.y;

    // near-tie guard: distance to the chosen interval's boundaries
    const float EPS = 1e-5f;
    const float g0 = fminf(r0 - pa.x, pa.z - r0);
    const float g1 = fminf(r1 - pb.x, pb.z - r1);
    if (g0 < EPS || g1 < EPS) {
        // fp64 recompute for this pair (rare, exec-masked)
        const double v0d = (double)x0 * invd;
        const double v1d = (double)x1 * invd;
        const double cd = (double)c, sd = (double)s;
        const double r0d = cd * v0d - sd * v1d;
        const double r1d = sd * v0d + cd * v1d;
        a = 0; b = 0;
        double q0d = (double)cent[0], q1d = (double)cent[0];
#pragma unroll
        for (int j = 0; j < 15; ++j) {
            const double mj = 0.5 * ((double)cent[j] + (double)cent[j + 1]);  // exact
            const bool ca = r0d > mj;
            const bool cb = r1d > mj;
            a += ca ? 1 : 0;
            b += cb ? 1 : 0;
            q0d = ca ? (double)cent[j + 1] : q0d;
            q1d = cb ? (double)cent[j + 1] : q1d;
        }
        q0 = (float)q0d;
        q1 = (float)q1d;
    }

    // dequant + inverse rotate + rescale (comparison is bf16-granular)
    QP r;
    r.o0 = (c * q0 + s * q1) * dnf;
    r.o1 = (c * q1 - s * q0) * dnf;
    r.i0 = (float)a;
    r.i1 = (float)b;
    return r;
}

__global__ __launch_bounds__(BLOCK_T) void planar_quant_kernel(
    const float* __restrict__ x,
    const float* __restrict__ cent,
    const float* __restrict__ rot2,
    float* __restrict__ out_xhat,
    float* __restrict__ out_idx)
{
    const int row = blockIdx.x;
    const int t   = threadIdx.x;

    const f32x4* xr = (const f32x4*)(x + (size_t)row * ROW_D);
    const float4* rr = (const float4*)rot2;   // float4 f covers pairs 2f, 2f+1

    __shared__ f32x4  xs[ROW_D / 4];   // 16 KB row stash: frees 32 VGPRs
    __shared__ double smem[5];
    __shared__ float4 w4[16];          // (md[k-1], cd[k], md[k], 0); ends = +-inf

    // Phase 1: stream row -> LDS (nontemporal global read: read-once),
    // fp64 sum of squares. Only `ss` lives across the barrier.
    double ss = 0.0;
#pragma unroll
    for (int i = 0; i < F4_PER_T; ++i) {
        f32x4 v = __builtin_nontemporal_load(&xr[t + BLOCK_T * i]);
        xs[t + BLOCK_T * i] = v;
        ss += (double)v.x * (double)v.x;
        ss += (double)v.y * (double)v.y;
        ss += (double)v.z * (double)v.z;
        ss += (double)v.w * (double)v.w;
    }

#pragma unroll
    for (int off = 32; off > 0; off >>= 1)
        ss += __shfl_down(ss, off, 64);

    const int wid = t >> 6;
    if ((t & 63) == 0) smem[wid] = ss;

    // centroids + midpoints in fp32 (uniform loads -> scalar regs)
    float cf[16];
#pragma unroll
    for (int j = 0; j < 16; ++j) cf[j] = cent[j];
    float mf[15];
#pragma unroll
    for (int j = 0; j < 15; ++j) mf[j] = 0.5f * (cf[j] + cf[j + 1]);

    if (t < 16) {
        const float lo = (t == 0)  ? -3.0e38f : 0.5f * (cf[t - 1] + cf[t]);
        const float hi = (t == 15) ?  3.0e38f : 0.5f * (cf[t] + cf[t + 1]);
        w4[t] = make_float4(lo, cf[t], hi, 0.0f);
    }
    __syncthreads();
    if (t == 0) {
        double tot = smem[0] + smem[1] + smem[2] + smem[3];
        double n = sqrt(tot);
        smem[4] = (n < 1e-8) ? 1e-8 : n;   // jnp.clip(norm, 1e-8)
    }
    __syncthreads();
    const double dnd  = smem[4];
    const double invd = 1.0 / dnd;
    const float  dnf  = (float)dnd;
    const float  invf = (float)invd;

    f32x4* xo = (f32x4*)(out_xhat + (size_t)row * ROW_D);
    f32x4* io = (f32x4*)(out_idx  + (size_t)row * ROW_D);

    // Phase 2: reload row from LDS (conflict-free b128), rot2 from L1/L2;
    // rotate/quantize/dequantize; nontemporal coalesced stores.
#pragma unroll
    for (int i = 0; i < F4_PER_T; ++i) {
        const int f = t + BLOCK_T * i;
        const f32x4 xv = xs[f];
        const float4 rv = rr[f];
        const QP lo = quant_pair(xv.x, xv.y, rv.x, rv.y, invf, dnf, invd, mf, w4, cent);
        const QP hi = quant_pair(xv.z, xv.w, rv.z, rv.w, invf, dnf, invd, mf, w4, cent);
        f32x4 ov, iv;
        ov.x = lo.o0; ov.y = lo.o1; ov.z = hi.o0; ov.w = hi.o1;
        iv.x = lo.i0; iv.y = lo.i1; iv.z = hi.i0; iv.w = hi.i1;
        __builtin_nontemporal_store(ov, &xo[f]);
        __builtin_nontemporal_store(iv, &io[f]);
    }
}

extern "C" void kernel_launch(void* const* d_in, const int* in_sizes, int n_in,
                              void* d_out, int out_size, void* d_ws, size_t ws_size,
                              hipStream_t stream) {
    const float* x    = (const float*)d_in[0];
    const float* cent = (const float*)d_in[1];
    const float* rot2 = (const float*)d_in[2];

    const int d = in_sizes[2];           // 2*n_groups = 4096
    const int B = in_sizes[0] / d;       // 4096

    float* out  = (float*)d_out;
    float* xhat = out;                   // output 0: x_hat (B*d fp32)
    float* idxo = out + (size_t)B * d;   // output 1: indices as fp32 values

    planar_quant_kernel<<<B, BLOCK_T, 0, stream>>>(x, cent, rot2, xhat, idxo);
}